// Round 7
// baseline (283.441 us; speedup 1.0000x reference)
//
#include <hip/hip_runtime.h>

#define N_NODES   50000
#define N_EDGES   800000
#define IN_DIM    100
#define HIDDEN    16
#define N_CLASSES 40

// Bucketing geometry: bucket = dst >> 6 (64 nodes per bucket)
#define BSHIFT 6
#define NPB    64                        // nodes per bucket
#define NBKT   782                       // ceil(N_NODES / NPB)
#define PB     256                       // partition blocks
#define EPB    3125                      // edges per partition block (256*3125 = 800000)
#define EPT    7                         // max edges in regs per thread (ceil(3125/512))
#define CAP    2048                      // per-bucket edge capacity (mean 1024, sd 32)
#define GEMMB  782                       // gemm sub-grid: ceil(50000/64)

// K1 LDS union:
//  partition: cnt[800 ints]@0 | lcur[800 ints]@3200 | wpre[8 ints]@6400
//             | staged int2[3125]@8448 .. 33448
//  gemm:      sX[64*100]@0 .. 25600 | sW[1600]@25600 .. 32000
#define K1_LDS 33456

// ---------------------------------------------------------------------------
// K1: blocks [0,PB) partition the edge list (edges held in REGISTERS between
// count and scatter -> single global read); blocks [PB, PB+GEMMB) compute
// y1 = X @ W1 concurrently. Scan is 2-barrier shfl wave-scan (was 18-barrier).
// BTt transposed: BTt[k*PB + b] = start of bucket k's run in block b's region.
// Payload: {src | dst_low6 << 16, val}.
// ---------------------------------------------------------------------------
__global__ __launch_bounds__(512) void build_and_gemm(const int* __restrict__ src,
                                                      const int* __restrict__ dst,
                                                      const float* __restrict__ val,
                                                      const float* __restrict__ X,
                                                      const float* __restrict__ W,
                                                      int* __restrict__ BTt,
                                                      int2* __restrict__ binned,
                                                      float* __restrict__ Y) {
    __shared__ __align__(16) char smem[K1_LDS];
    const int tid = threadIdx.x;

    if (blockIdx.x < PB) {
        // ---------------- partition path ----------------
        int*  cnt    = (int*)smem;
        int*  lcur   = (int*)(smem + 3200);
        int*  wpre   = (int*)(smem + 6400);
        int2* staged = (int2*)(smem + 8448);
        const int b = blockIdx.x, e0 = b * EPB;
        const int lane = tid & 63, w = tid >> 6;      // 8 waves

        for (int k = tid; k < NBKT; k += 512) cnt[k] = 0;
        __syncthreads();

        // single global read: hold edges in registers, count buckets
        int pk[EPT], ps[EPT]; float pv[EPT];
#pragma unroll
        for (int q = 0; q < EPT; ++q) {
            const int i = tid + q * 512;
            if (i < EPB) {
                const int e = e0 + i;
                const int d = dst[e];
                pk[q] = d >> BSHIFT;
                ps[q] = src[e] | ((d & (NPB - 1)) << 16);
                pv[q] = val[e];
                atomicAdd(&cnt[pk[q]], 1);
            } else pk[q] = -1;
        }
        __syncthreads();

        // 2-barrier exclusive scan over 782 buckets (2 buckets per thread)
        const int k0 = 2 * tid, k1 = 2 * tid + 1;
        const int a  = (k0 < NBKT) ? cnt[k0] : 0;
        const int bb = (k1 < NBKT) ? cnt[k1] : 0;
        const int s  = a + bb;
        int x = s;
#pragma unroll
        for (int d = 1; d < 64; d <<= 1) {
            const int y = __shfl_up(x, d, 64);
            if (lane >= d) x += y;
        }
        if (lane == 63) wpre[w] = x;
        __syncthreads();
        int add = 0;
        for (int i = 0; i < w; ++i) add += wpre[i];
        const int excl = add + x - s;
        if (k0 < NBKT) { lcur[k0] = excl;     BTt[k0 * PB + b] = excl; }
        if (k1 < NBKT) { lcur[k1] = excl + a; BTt[k1 * PB + b] = excl + a; }
        if (tid == 0)  BTt[NBKT * PB + b] = EPB;
        __syncthreads();

        // scatter from registers into LDS, bucket-grouped
#pragma unroll
        for (int q = 0; q < EPT; ++q) {
            if (pk[q] >= 0) {
                const int pos = atomicAdd(&lcur[pk[q]], 1);
                staged[pos] = make_int2(ps[q], __float_as_int(pv[q]));
            }
        }
        __syncthreads();

        // linear coalesced copy-out
        for (int i = tid; i < EPB; i += 512)
            binned[e0 + i] = staged[i];
    } else {
        // ---------------- gemm path: 64 rows, thread = (row, float2-col) ----
        float* sX = (float*)smem;
        float* sW = (float*)(smem + 25600);
        const int b2   = blockIdx.x - PB;
        const int row0 = b2 * 64;
        const int nrows = min(64, N_NODES - row0);

        const float4* W4 = (const float4*)W;
        float4* sW4 = (float4*)sW;
        for (int i = tid; i < (IN_DIM * HIDDEN) / 4; i += 512) sW4[i] = W4[i];
        const float4* X4 = (const float4*)(X + (size_t)row0 * IN_DIM);
        float4* sX4 = (float4*)sX;
        const int nf4 = nrows * (IN_DIM / 4);
        for (int i = tid; i < nf4; i += 512) sX4[i] = X4[i];
        __syncthreads();

        const int r = tid >> 3, hh = tid & 7;
        if (r >= nrows) return;
        float2 acc = make_float2(0.f, 0.f);
        const float* xr = &sX[r * IN_DIM];
#pragma unroll
        for (int k = 0; k < IN_DIM; ++k) {
            const float xk = xr[k];
            const float2 wv = *(const float2*)&sW[k * HIDDEN + hh * 2];
            acc.x = fmaf(xk, wv.x, acc.x);
            acc.y = fmaf(xk, wv.y, acc.y);
        }
        *(float2*)&Y[(size_t)(row0 + r) * HIDDEN + hh * 2] = acc;
    }
}

// ---------------------------------------------------------------------------
// K2'/K3': per-bucket LDS-accumulate SpMM (NO node sort). Stage bucket edges
// into LDS once, then 16 lanes/edge: acc[n*16+j] += v * X[s*16+j] via native
// ds_add_f32 (unsafeAtomicAdd). Zero loop-carried deps in the edge loop.
//  IS_OUT=false: Z = relu(acc)  (z1 write, coalesced float4)
//  IS_OUT=true : out = log_softmax(acc @ W2) computed in-block
// ---------------------------------------------------------------------------
template <bool IS_OUT>
__global__ __launch_bounds__(256) void spmm_bucket2(const int* __restrict__ BTt,
                                                    const int2* __restrict__ binned,
                                                    const float* __restrict__ X,
                                                    const float* __restrict__ W2,
                                                    float* __restrict__ outp) {
    __shared__ int2  raw[CAP];              // 16 KB
    __shared__ float acc[NPB * HIDDEN];     // 4 KB
    __shared__ int   wpre[4];
    __shared__ float sW[HIDDEN * N_CLASSES];// 2.56 KB (used when IS_OUT)
    const int tid = threadIdx.x, k = blockIdx.x;
    const int lane = tid & 63, w = tid >> 6;

    for (int i = tid; i < NPB * HIDDEN; i += 256) acc[i] = 0.f;
    if (IS_OUT)
        for (int i = tid; i < HIDDEN * N_CLASSES; i += 256) sW[i] = W2[i];

    // coalesced run boundaries; shfl scan of 256 run lengths -> LDS offsets
    const int rs = BTt[k * PB + tid];
    const int re = BTt[(k + 1) * PB + tid];
    const int len = re - rs;
    int x = len;
#pragma unroll
    for (int d = 1; d < 64; d <<= 1) {
        const int y = __shfl_up(x, d, 64);
        if (lane >= d) x += y;
    }
    if (lane == 63) wpre[w] = x;
    __syncthreads();                         // covers acc zero + sW + wpre
    int add = 0;
    for (int i = 0; i < w; ++i) add += wpre[i];
    const int tot = wpre[0] + wpre[1] + wpre[2] + wpre[3];

    // single global read: stage this bucket's runs into LDS
    int o = add + x - len;
    const int2* rb = binned + (size_t)tid * EPB;
    for (int p = rs; p < re; ++p, ++o) raw[o] = rb[p];
    __syncthreads();

    // accumulate: 16 lanes per edge, fire-and-forget ds_add_f32
    const int j = tid & 15;
    for (int i = tid >> 4; i < tot; i += 16) {
        const int2 e = raw[i];
        const int  sn = e.x & 0xFFFF;
        const int  n  = (e.x >> 16) & (NPB - 1);
        const float v = __int_as_float(e.y);
        const float xv = X[(size_t)sn * HIDDEN + j];
        unsafeAtomicAdd(&acc[n * HIDDEN + j], v * xv);
    }
    __syncthreads();

    if (!IS_OUT) {
        // z1 = relu(acc): 4 threads per node, float4
        const int node = k * NPB + (tid >> 2);
        if (node >= N_NODES) return;
        float4 o4 = *(const float4*)&acc[tid * 4];
        o4.x = fmaxf(o4.x, 0.f); o4.y = fmaxf(o4.y, 0.f);
        o4.z = fmaxf(o4.z, 0.f); o4.w = fmaxf(o4.w, 0.f);
        ((float4*)outp)[(size_t)node * 4 + (tid & 3)] = o4;
    } else {
        // head: 4 lanes per node, lane q owns classes [10q, 10q+10)
        const int g = tid >> 2, q = tid & 3;
        const int n = k * NPB + g;
        if (n >= N_NODES) return;
        float oc[10];
#pragma unroll
        for (int c = 0; c < 10; ++c) oc[c] = 0.f;
        const float* zr = &acc[g * HIDDEN];
#pragma unroll
        for (int kk = 0; kk < HIDDEN; ++kk) {
            const float zk = zr[kk];
            const float* wr = &sW[kk * N_CLASSES + q * 10];
#pragma unroll
            for (int c = 0; c < 10; ++c) oc[c] = fmaf(zk, wr[c], oc[c]);
        }
        float m = oc[0];
#pragma unroll
        for (int c = 1; c < 10; ++c) m = fmaxf(m, oc[c]);
#pragma unroll
        for (int d = 1; d < 4; d <<= 1) m = fmaxf(m, __shfl_xor(m, d, 4));
        float se = 0.f;
#pragma unroll
        for (int c = 0; c < 10; ++c) se += __expf(oc[c] - m);
#pragma unroll
        for (int d = 1; d < 4; d <<= 1) se += __shfl_xor(se, d, 4);
        const float lse = m + __logf(se);

        float* orow = outp + (size_t)n * N_CLASSES + q * 10;
#pragma unroll
        for (int c = 0; c < 10; ++c) orow[c] = oc[c] - lse;
    }
}

extern "C" void kernel_launch(void* const* d_in, const int* in_sizes, int n_in,
                              void* d_out, int out_size, void* d_ws, size_t ws_size,
                              hipStream_t stream) {
    const float* features = (const float*)d_in[0];  // [50000,100]
    const int*   edge_src = (const int*)d_in[1];    // [800000]
    const int*   edge_dst = (const int*)d_in[2];    // [800000]
    const float* edge_val = (const float*)d_in[3];  // [800000]
    const float* W1       = (const float*)d_in[4];  // [100,16]
    const float* W2       = (const float*)d_in[5];  // [16,40]
    float*       out      = (float*)d_out;          // [50000,40]

    char* base = (char*)d_ws;
    const size_t HNB = (size_t)N_NODES * HIDDEN * sizeof(float);     // 3.2 MB
    float* y1     = (float*)(base);
    float* z1     = (float*)(base + HNB);
    int2*  binned = (int2*) (base + 2 * HNB);                        // 6.4 MB
    int*   BTt    = (int*)  (base + 2 * HNB + (size_t)N_EDGES * 8);  // ~802 KB

    // K1: partition (blocks 0..255) || gemm y1 = X@W1 (blocks 256..1037)
    build_and_gemm<<<PB + GEMMB, 512, 0, stream>>>(edge_src, edge_dst, edge_val,
                                                   features, W1, BTt, binned, y1);
    // K2': z1 = relu(A @ y1), per-bucket LDS accumulate
    spmm_bucket2<false><<<NBKT, 256, 0, stream>>>(BTt, binned, y1, nullptr, z1);
    // K3': out = log_softmax((A @ z1) @ W2), accumulate + head in one block
    spmm_bucket2<true><<<NBKT, 256, 0, stream>>>(BTt, binned, z1, W2, out);
}

// Round 8
// 129.732 us; speedup vs baseline: 2.1848x; 2.1848x over previous
//
#include <hip/hip_runtime.h>

#define N_NODES   50000
#define N_EDGES   800000
#define IN_DIM    100
#define HIDDEN    16
#define N_CLASSES 40

// Bucketing geometry: bucket = dst >> 6 (64 nodes per bucket)
#define BSHIFT 6
#define NPB    64                        // nodes per bucket
#define NBKT   782                       // ceil(N_NODES / NPB)
#define PB     500                       // partition blocks/regions
#define EPB    1600                      // edges per region (500*1600 = 800000 exact)
#define EPT    7                         // max edges in regs per thread (ceil(1600/256))
#define CAP    2048                      // per-bucket capacity (mean 1024, sd 32)
#define GROWS  32                        // gemm rows per block
#define GEMMB  1563                      // ceil(50000/32)
#define GNODES 32                        // nodes per gather_out block (8 lanes/node)

// K1 LDS union (19264 B -> 8 blocks/CU at 256 thr = full occupancy):
//  partition: cnt[782]@0(pad 3200) | lcur[782]@3200(pad 6400) | wpre[4]@6400
//             | staged int2[1600]@6464 .. 19264
//  gemm:      sX[32*100]@0 .. 12800 | sW[1600]@12800 .. 19200
#define K1_LDS 19264

// ---------------------------------------------------------------------------
// K1: blocks [0,PB) partition the edge list (edges held in REGISTERS between
// count and scatter -> single global read); blocks [PB, PB+GEMMB) compute
// y1 = X @ W1 concurrently. 256-thread blocks, 19.3 KB LDS -> 8 blocks/CU.
// BTt transposed: BTt[k*PB + b] = start of bucket k's run in region b.
// Payload: {src | dst_low6 << 16, val}.
// ---------------------------------------------------------------------------
__global__ __launch_bounds__(256) void build_and_gemm(const int* __restrict__ src,
                                                      const int* __restrict__ dst,
                                                      const float* __restrict__ val,
                                                      const float* __restrict__ X,
                                                      const float* __restrict__ W,
                                                      int* __restrict__ BTt,
                                                      int2* __restrict__ binned,
                                                      float* __restrict__ Y) {
    __shared__ __align__(16) char smem[K1_LDS];
    const int tid = threadIdx.x;

    if (blockIdx.x < PB) {
        // ---------------- partition path ----------------
        int*  cnt    = (int*)smem;
        int*  lcur   = (int*)(smem + 3200);
        int*  wpre   = (int*)(smem + 6400);
        int2* staged = (int2*)(smem + 6464);
        const int b = blockIdx.x, e0 = b * EPB;
        const int lane = tid & 63, w = tid >> 6;      // 4 waves

        for (int k = tid; k < NBKT; k += 256) cnt[k] = 0;
        __syncthreads();

        // single global read: hold edges in registers, count buckets
        int pk[EPT], ps[EPT]; float pv[EPT];
#pragma unroll
        for (int q = 0; q < EPT; ++q) {
            const int i = tid + q * 256;
            if (i < EPB) {
                const int e = e0 + i;
                const int d = dst[e];
                pk[q] = d >> BSHIFT;
                ps[q] = src[e] | ((d & (NPB - 1)) << 16);
                pv[q] = val[e];
                atomicAdd(&cnt[pk[q]], 1);
            } else pk[q] = -1;
        }
        __syncthreads();

        // exclusive scan over 782 buckets: 4 buckets/thread + shfl wave-scan
        int c[4], s = 0;
#pragma unroll
        for (int u = 0; u < 4; ++u) {
            const int kk = 4 * tid + u;
            c[u] = (kk < NBKT) ? cnt[kk] : 0;
            s += c[u];
        }
        int x = s;
#pragma unroll
        for (int d = 1; d < 64; d <<= 1) {
            const int y = __shfl_up(x, d, 64);
            if (lane >= d) x += y;
        }
        if (lane == 63) wpre[w] = x;
        __syncthreads();
        int add = 0;
        for (int i = 0; i < w; ++i) add += wpre[i];
        int run = add + x - s;
#pragma unroll
        for (int u = 0; u < 4; ++u) {
            const int kk = 4 * tid + u;
            if (kk < NBKT) {
                lcur[kk] = run;
                BTt[kk * PB + b] = run;
                run += c[u];
            }
        }
        if (tid == 0) BTt[NBKT * PB + b] = EPB;
        __syncthreads();

        // scatter from registers into LDS, bucket-grouped
#pragma unroll
        for (int q = 0; q < EPT; ++q) {
            if (pk[q] >= 0) {
                const int pos = atomicAdd(&lcur[pk[q]], 1);
                staged[pos] = make_int2(ps[q], __float_as_int(pv[q]));
            }
        }
        __syncthreads();

        // linear coalesced copy-out
        for (int i = tid; i < EPB; i += 256)
            binned[e0 + i] = staged[i];
    } else {
        // ---------------- gemm path: 32 rows, thread = (row, float2-col) ----
        float* sX = (float*)smem;
        float* sW = (float*)(smem + 12800);
        const int b2   = blockIdx.x - PB;
        const int row0 = b2 * GROWS;
        const int nrows = min(GROWS, N_NODES - row0);

        const float4* W4 = (const float4*)W;
        float4* sW4 = (float4*)sW;
        for (int i = tid; i < (IN_DIM * HIDDEN) / 4; i += 256) sW4[i] = W4[i];
        const float4* X4 = (const float4*)(X + (size_t)row0 * IN_DIM);
        float4* sX4 = (float4*)sX;
        const int nf4 = nrows * (IN_DIM / 4);
        for (int i = tid; i < nf4; i += 256) sX4[i] = X4[i];
        __syncthreads();

        const int r = tid >> 3, hh = tid & 7;
        if (r >= nrows) return;
        float2 acc = make_float2(0.f, 0.f);
        const float* xr = &sX[r * IN_DIM];
#pragma unroll
        for (int kk = 0; kk < IN_DIM; ++kk) {
            const float xk = xr[kk];
            const float2 wv = *(const float2*)&sW[kk * HIDDEN + hh * 2];
            acc.x = fmaf(xk, wv.x, acc.x);
            acc.y = fmaf(xk, wv.y, acc.y);
        }
        *(float2*)&Y[(size_t)(row0 + r) * HIDDEN + hh * 2] = acc;
    }
}

// ---------------------------------------------------------------------------
// K2: per-bucket node sort (two light passes over binned, ranks into 16 KB
// LDS -> 8 blocks/CU) + write sorted/meta for K3 + fused gather1:
// z1 = relu(A @ y1), 4 lanes/node, float4, unroll x2.
// ---------------------------------------------------------------------------
__global__ __launch_bounds__(256) void sort_gather(const int* __restrict__ BTt,
                                                   const int2* __restrict__ binned,
                                                   const float* __restrict__ Xin,
                                                   int2* __restrict__ sorted,
                                                   int2* __restrict__ meta,
                                                   float* __restrict__ Z) {
    __shared__ int2 srt[CAP];          // 16 KB: node-sorted bucket edges
    __shared__ int  cnt[NPB];
    __shared__ int  cur[NPB];
    __shared__ int  sPad;
    const int tid = threadIdx.x, k = blockIdx.x;

    if (tid < NPB) cnt[tid] = 0;

    // run boundaries: runs tid and tid+256 (coalesced reads of transposed BTt)
    const int rs0 = BTt[k * PB + tid];
    const int re0 = BTt[(k + 1) * PB + tid];
    const int rr1 = tid + 256;
    int rs1 = 0, re1 = 0;
    if (rr1 < PB) { rs1 = BTt[k * PB + rr1]; re1 = BTt[(k + 1) * PB + rr1]; }
    __syncthreads();

    // pass 1: node histogram
    for (int p = rs0; p < re0; ++p)
        atomicAdd(&cnt[(binned[(size_t)tid * EPB + p].x >> 16) & (NPB - 1)], 1);
    if (rr1 < PB)
        for (int p = rs1; p < re1; ++p)
            atomicAdd(&cnt[(binned[(size_t)rr1 * EPB + p].x >> 16) & (NPB - 1)], 1);
    __syncthreads();

    // wave scan with even-pad (16B-aligned segments for K3's int4 loads)
    if (tid < NPB) {
        const int v  = cnt[tid];
        const int vp = (v + 1) & ~1;
        int x = vp;
#pragma unroll
        for (int d = 1; d < 64; d <<= 1) {
            const int y = __shfl_up(x, d, 64);
            if (tid >= d) x += y;
        }
        const int excl = x - vp;
        cur[tid] = excl;
        const int node = k * NPB + tid;
        if (node < N_NODES) meta[node] = make_int2(k * CAP + excl, v);
        if (tid == NPB - 1) sPad = x;
    }
    __syncthreads();

    // pass 2: rank-scatter into LDS (binned re-read, L2-hot)
    for (int p = rs0; p < re0; ++p) {
        const int2 e = binned[(size_t)tid * EPB + p];
        const int pos = atomicAdd(&cur[(e.x >> 16) & (NPB - 1)], 1);
        srt[pos] = make_int2(e.x & 0xFFFF, e.y);
    }
    if (rr1 < PB)
        for (int p = rs1; p < re1; ++p) {
            const int2 e = binned[(size_t)rr1 * EPB + p];
            const int pos = atomicAdd(&cur[(e.x >> 16) & (NPB - 1)], 1);
            srt[pos] = make_int2(e.x & 0xFFFF, e.y);
        }
    __syncthreads();

    // coalesced copy-out for K3
    const int padTot = sPad;
    for (int i = tid; i < padTot; i += 256)
        sorted[(size_t)k * CAP + i] = srt[i];

    // fused gather1: 4 lanes per node, float4 of the 16-wide row, unroll x2
    const int g = tid >> 2, q = tid & 3;
    const int node = k * NPB + g;
    if (node >= N_NODES) return;
    const int deg = cnt[g];
    const int beg = cur[g] - deg;      // cur[g] == excl + deg after ranking
    const float4* X4 = (const float4*)Xin;
    float4 acc = make_float4(0.f, 0.f, 0.f, 0.f);
    int p = beg;
    for (; p + 2 <= beg + deg; p += 2) {
        const int2 e0 = srt[p];
        const int2 e1 = srt[p + 1];
        const float v0 = __int_as_float(e0.y);
        const float v1 = __int_as_float(e1.y);
        const float4 x0 = X4[(size_t)e0.x * 4 + q];
        const float4 x1 = X4[(size_t)e1.x * 4 + q];
        acc.x = fmaf(v0, x0.x, acc.x); acc.y = fmaf(v0, x0.y, acc.y);
        acc.z = fmaf(v0, x0.z, acc.z); acc.w = fmaf(v0, x0.w, acc.w);
        acc.x = fmaf(v1, x1.x, acc.x); acc.y = fmaf(v1, x1.y, acc.y);
        acc.z = fmaf(v1, x1.z, acc.z); acc.w = fmaf(v1, x1.w, acc.w);
    }
    if (p < beg + deg) {
        const int2 e = srt[p];
        const float v = __int_as_float(e.y);
        const float4 xv = X4[(size_t)e.x * 4 + q];
        acc.x = fmaf(v, xv.x, acc.x); acc.y = fmaf(v, xv.y, acc.y);
        acc.z = fmaf(v, xv.z, acc.z); acc.w = fmaf(v, xv.w, acc.w);
    }
    acc.x = fmaxf(acc.x, 0.f); acc.y = fmaxf(acc.y, 0.f);
    acc.z = fmaxf(acc.z, 0.f); acc.w = fmaxf(acc.w, 0.f);
    ((float4*)Z)[(size_t)node * 4 + q] = acc;
}

// ---------------------------------------------------------------------------
// K3: z2 = A @ z1 (8-lane register gather) -> padded LDS transpose ->
// out = log_softmax(z2 @ W2). Lane j owns classes [5j, 5j+5); width-8 shfl.
// ---------------------------------------------------------------------------
__global__ __launch_bounds__(256) void gather_out(const int2* __restrict__ meta,
                                                  const int2* __restrict__ sorted,
                                                  const float* __restrict__ X,
                                                  const float* __restrict__ W2,
                                                  float* __restrict__ out) {
    __shared__ float sW[HIDDEN * N_CLASSES];   // 2.56 KB
    __shared__ float zt[GNODES * 17];          // +1 pad: conflict-free transpose
    const int tid = threadIdx.x;
    for (int i = tid; i < HIDDEN * N_CLASSES; i += 256) sW[i] = W2[i];

    const int g = tid >> 3, j = tid & 7;
    const int n = blockIdx.x * GNODES + g;

    float2 acc = make_float2(0.f, 0.f);
    if (n < N_NODES) {
        const int2 md = meta[n];
        const int beg = md.x, end = md.x + md.y;
        const float2* X2 = (const float2*)X;
        int p = beg;
        for (; p + 4 <= end; p += 4) {
            const int4 ea = *(const int4*)&sorted[p];
            const int4 eb = *(const int4*)&sorted[p + 2];
            const float2 x0 = X2[(size_t)ea.x * 8 + j];
            const float2 x1 = X2[(size_t)ea.z * 8 + j];
            const float2 x2 = X2[(size_t)eb.x * 8 + j];
            const float2 x3 = X2[(size_t)eb.z * 8 + j];
            const float v0 = __int_as_float(ea.y), v1 = __int_as_float(ea.w);
            const float v2 = __int_as_float(eb.y), v3 = __int_as_float(eb.w);
            acc.x = fmaf(v0, x0.x, acc.x); acc.y = fmaf(v0, x0.y, acc.y);
            acc.x = fmaf(v1, x1.x, acc.x); acc.y = fmaf(v1, x1.y, acc.y);
            acc.x = fmaf(v2, x2.x, acc.x); acc.y = fmaf(v2, x2.y, acc.y);
            acc.x = fmaf(v3, x3.x, acc.x); acc.y = fmaf(v3, x3.y, acc.y);
        }
        for (; p < end; ++p) {
            const int2 e = sorted[p];
            const float2 xv = X2[(size_t)e.x * 8 + j];
            const float v = __int_as_float(e.y);
            acc.x = fmaf(v, xv.x, acc.x); acc.y = fmaf(v, xv.y, acc.y);
        }
    }
    zt[g * 17 + j * 2]     = acc.x;
    zt[g * 17 + j * 2 + 1] = acc.y;
    __syncthreads();
    if (n >= N_NODES) return;

    float z[HIDDEN];
#pragma unroll
    for (int k = 0; k < HIDDEN; ++k) z[k] = zt[g * 17 + k];

    float o[5];
#pragma unroll
    for (int i = 0; i < 5; ++i) o[i] = 0.f;
#pragma unroll
    for (int k = 0; k < HIDDEN; ++k) {
        const float zk = z[k];
#pragma unroll
        for (int i = 0; i < 5; ++i)
            o[i] = fmaf(zk, sW[k * N_CLASSES + j * 5 + i], o[i]);
    }

    float m = o[0];
#pragma unroll
    for (int i = 1; i < 5; ++i) m = fmaxf(m, o[i]);
#pragma unroll
    for (int d = 1; d < 8; d <<= 1) m = fmaxf(m, __shfl_xor(m, d, 8));
    float se = 0.f;
#pragma unroll
    for (int i = 0; i < 5; ++i) se += __expf(o[i] - m);
#pragma unroll
    for (int d = 1; d < 8; d <<= 1) se += __shfl_xor(se, d, 8);
    const float lse = m + __logf(se);

    float* orow = out + (size_t)n * N_CLASSES + j * 5;
#pragma unroll
    for (int i = 0; i < 5; ++i) orow[i] = o[i] - lse;
}

extern "C" void kernel_launch(void* const* d_in, const int* in_sizes, int n_in,
                              void* d_out, int out_size, void* d_ws, size_t ws_size,
                              hipStream_t stream) {
    const float* features = (const float*)d_in[0];  // [50000,100]
    const int*   edge_src = (const int*)d_in[1];    // [800000]
    const int*   edge_dst = (const int*)d_in[2];    // [800000]
    const float* edge_val = (const float*)d_in[3];  // [800000]
    const float* W1       = (const float*)d_in[4];  // [100,16]
    const float* W2       = (const float*)d_in[5];  // [16,40]
    float*       out      = (float*)d_out;          // [50000,40]

    char* base = (char*)d_ws;
    const size_t HNB = (size_t)N_NODES * HIDDEN * sizeof(float);       // 3.2 MB
    float* y1     = (float*)(base);
    float* z1     = (float*)(base + HNB);
    int2*  binned = (int2*) (base + 2 * HNB);                          // 6.4 MB
    int2*  sortd  = (int2*) (base + 2 * HNB + (size_t)N_EDGES * 8);    // 12.8 MB
    char*  tail   = base + 2 * HNB + (size_t)N_EDGES * 8
                         + (size_t)NBKT * CAP * 8;
    int*   BTt    = (int*) (tail);                                     // 783*500*4 ≈ 1.57 MB
    int2*  meta   = (int2*)(tail + (((size_t)(NBKT + 1) * PB * 4 + 255) & ~255ULL));

    // K1: partition (blocks 0..499) || gemm y1 = X@W1 (blocks 500..2062)
    build_and_gemm<<<PB + GEMMB, 256, 0, stream>>>(edge_src, edge_dst, edge_val,
                                                   features, W1, BTt, binned, y1);
    // K2: per-bucket LDS sort -> sorted/meta + fused z1 = relu(A @ y1)
    sort_gather<<<NBKT, 256, 0, stream>>>(BTt, binned, y1, sortd, meta, z1);
    // K3: z2 = A @ z1 fused with log_softmax(z2 @ W2)
    gather_out<<<(N_NODES + GNODES - 1) / GNODES, 256, 0, stream>>>(meta, sortd, z1, W2, out);
}

// Round 10
// 128.641 us; speedup vs baseline: 2.2034x; 1.0085x over previous
//
#include <hip/hip_runtime.h>

#define N_NODES   50000
#define N_EDGES   800000
#define IN_DIM    100
#define HIDDEN    16
#define N_CLASSES 40

// Bucketing geometry: bucket = dst >> 6 (64 nodes per bucket)
#define BSHIFT 6
#define NPB    64                        // nodes per bucket
#define NBKT   782                       // ceil(N_NODES / NPB)
#define PB     256                       // partition blocks/regions
#define EPB    3125                      // edges per region (256*3125 = 800000)
#define EPT    7                         // max edges in regs/thread (ceil(3125/512))
#define CAP    2048                      // per-bucket capacity (mean 1024, sd 32)
#define GEMMB  782                       // gemm tiles of 64 rows

// K1 LDS union:
//  partition: cnt[782]@0(3200) | lcur@3200(3200) | wpre[8]@6400
//             | staged int2[3125]@8448 .. 33448
//  gemm:      sX[64*100]@0 .. 25600 | sW[1600]@25600 .. 32000
#define K1_LDS 33456

// ---------------------------------------------------------------------------
// K1: blocks [0,PB) partition the edge list (edges held in REGISTERS between
// count and scatter -> single global read); blocks [PB, PB+GEMMB) compute
// y1 = X @ W1 concurrently. Verified in round 7.
// BTt transposed: BTt[k*PB + b] = start of bucket k's run in region b.
// Payload: {src | dst_low6 << 16, val}.
// ---------------------------------------------------------------------------
__global__ __launch_bounds__(512) void build_and_gemm(const int* __restrict__ src,
                                                      const int* __restrict__ dst,
                                                      const float* __restrict__ val,
                                                      const float* __restrict__ X,
                                                      const float* __restrict__ W,
                                                      int* __restrict__ BTt,
                                                      int2* __restrict__ binned,
                                                      float* __restrict__ Y) {
    __shared__ __align__(16) char smem[K1_LDS];
    const int tid = threadIdx.x;

    if (blockIdx.x < PB) {
        // ---------------- partition path ----------------
        int*  cnt    = (int*)smem;
        int*  lcur   = (int*)(smem + 3200);
        int*  wpre   = (int*)(smem + 6400);
        int2* staged = (int2*)(smem + 8448);
        const int b = blockIdx.x, e0 = b * EPB;
        const int lane = tid & 63, w = tid >> 6;      // 8 waves

        for (int k = tid; k < NBKT; k += 512) cnt[k] = 0;
        __syncthreads();

        // single global read: hold edges in registers, count buckets
        int pk[EPT], ps[EPT]; float pv[EPT];
#pragma unroll
        for (int q = 0; q < EPT; ++q) {
            const int i = tid + q * 512;
            if (i < EPB) {
                const int e = e0 + i;
                const int d = dst[e];
                pk[q] = d >> BSHIFT;
                ps[q] = src[e] | ((d & (NPB - 1)) << 16);
                pv[q] = val[e];
                atomicAdd(&cnt[pk[q]], 1);
            } else pk[q] = -1;
        }
        __syncthreads();

        // exclusive scan over 782 buckets: 2 buckets/thread + shfl wave-scan
        const int k0 = 2 * tid, k1 = 2 * tid + 1;
        const int a  = (k0 < NBKT) ? cnt[k0] : 0;
        const int bb = (k1 < NBKT) ? cnt[k1] : 0;
        const int s  = a + bb;
        int x = s;
#pragma unroll
        for (int d = 1; d < 64; d <<= 1) {
            const int y = __shfl_up(x, d, 64);
            if (lane >= d) x += y;
        }
        if (lane == 63) wpre[w] = x;
        __syncthreads();
        int add = 0;
        for (int i = 0; i < w; ++i) add += wpre[i];
        const int excl = add + x - s;
        if (k0 < NBKT) { lcur[k0] = excl;     BTt[k0 * PB + b] = excl; }
        if (k1 < NBKT) { lcur[k1] = excl + a; BTt[k1 * PB + b] = excl + a; }
        if (tid == 0)  BTt[NBKT * PB + b] = EPB;
        __syncthreads();

        // scatter from registers into LDS, bucket-grouped
#pragma unroll
        for (int q = 0; q < EPT; ++q) {
            if (pk[q] >= 0) {
                const int pos = atomicAdd(&lcur[pk[q]], 1);
                staged[pos] = make_int2(ps[q], __float_as_int(pv[q]));
            }
        }
        __syncthreads();

        // linear coalesced copy-out
        for (int i = tid; i < EPB; i += 512)
            binned[e0 + i] = staged[i];
    } else {
        // ---------------- gemm path: 64 rows, thread = (row, float2-col) ----
        float* sX = (float*)smem;
        float* sW = (float*)(smem + 25600);
        const int b2   = blockIdx.x - PB;
        const int row0 = b2 * 64;
        const int nrows = min(64, N_NODES - row0);

        const float4* W4 = (const float4*)W;
        float4* sW4 = (float4*)sW;
        for (int i = tid; i < (IN_DIM * HIDDEN) / 4; i += 512) sW4[i] = W4[i];
        const float4* X4 = (const float4*)(X + (size_t)row0 * IN_DIM);
        float4* sX4 = (float4*)sX;
        const int nf4 = nrows * (IN_DIM / 4);
        for (int i = tid; i < nf4; i += 512) sX4[i] = X4[i];
        __syncthreads();

        const int r = tid >> 3, hh = tid & 7;
        if (r >= nrows) return;
        float2 acc = make_float2(0.f, 0.f);
        const float* xr = &sX[r * IN_DIM];
#pragma unroll
        for (int kk = 0; kk < IN_DIM; ++kk) {
            const float xk = xr[kk];
            const float2 wv = *(const float2*)&sW[kk * HIDDEN + hh * 2];
            acc.x = fmaf(xk, wv.x, acc.x);
            acc.y = fmaf(xk, wv.y, acc.y);
        }
        *(float2*)&Y[(size_t)(row0 + r) * HIDDEN + hh * 2] = acc;
    }
}

// ---------------------------------------------------------------------------
// Shared per-bucket in-LDS sort preamble (verified round 6), used by K2 & K3.
// After it: srt[0..tot) node-sorted; cnt[g]=deg; cur[g]=excl+deg.
// ---------------------------------------------------------------------------
__device__ __forceinline__ int bucket_sort_lds(const int* __restrict__ BTt,
                                               const int2* __restrict__ binned,
                                               int k, int tid,
                                               int2* raw, int2* srt,
                                               int* cnt, int* cur, int* aux) {
    const int lane = tid & 63, w = tid >> 6;
    if (tid < NPB) cnt[tid] = 0;

    // thread t owns region t's run for bucket k (coalesced BTt reads)
    const int rs = BTt[k * PB + tid];
    const int re = BTt[(k + 1) * PB + tid];
    const int len = re - rs;
    int x = len;
#pragma unroll
    for (int d = 1; d < 64; d <<= 1) {
        const int y = __shfl_up(x, d, 64);
        if (lane >= d) x += y;
    }
    if (lane == 63) aux[w] = x;
    __syncthreads();
    int add = 0;
    for (int i = 0; i < w; ++i) add += aux[i];
    const int tot = aux[0] + aux[1] + aux[2] + aux[3];

    // single global read: stage this bucket's runs into LDS
    int o = add + x - len;
    const int2* rb = binned + (size_t)tid * EPB;
    for (int p = rs; p < re; ++p, ++o) raw[o] = rb[p];
    __syncthreads();

    // node histogram (LDS only)
    for (int i = tid; i < tot; i += 256)
        atomicAdd(&cnt[(raw[i].x >> 16) & (NPB - 1)], 1);
    __syncthreads();

    // wave scan over 64 node counts
    if (tid < NPB) {
        const int v = cnt[tid];
        int xx = v;
#pragma unroll
        for (int d = 1; d < 64; d <<= 1) {
            const int y = __shfl_up(xx, d, 64);
            if (tid >= d) xx += y;
        }
        cur[tid] = xx - v;
    }
    __syncthreads();

    // rank-scatter LDS -> LDS
    for (int i = tid; i < tot; i += 256) {
        const int2 e = raw[i];
        const int pos = atomicAdd(&cur[(e.x >> 16) & (NPB - 1)], 1);
        srt[pos] = make_int2(e.x & 0xFFFF, e.y);
    }
    __syncthreads();
    return tot;
}

// 4-lane float4 CSR gather from LDS srt (verified as round-6 K2 gather).
__device__ __forceinline__ float4 gather4(const int2* srt, int beg, int deg,
                                          const float4* X4, int q) {
    float4 a = make_float4(0.f, 0.f, 0.f, 0.f);
    int p = beg;
    for (; p + 2 <= beg + deg; p += 2) {
        const int2 e0 = srt[p];
        const int2 e1 = srt[p + 1];
        const float v0 = __int_as_float(e0.y);
        const float v1 = __int_as_float(e1.y);
        const float4 x0 = X4[(size_t)e0.x * 4 + q];
        const float4 x1 = X4[(size_t)e1.x * 4 + q];
        a.x = fmaf(v0, x0.x, a.x); a.y = fmaf(v0, x0.y, a.y);
        a.z = fmaf(v0, x0.z, a.z); a.w = fmaf(v0, x0.w, a.w);
        a.x = fmaf(v1, x1.x, a.x); a.y = fmaf(v1, x1.y, a.y);
        a.z = fmaf(v1, x1.z, a.z); a.w = fmaf(v1, x1.w, a.w);
    }
    if (p < beg + deg) {
        const int2 e = srt[p];
        const float v = __int_as_float(e.y);
        const float4 xv = X4[(size_t)e.x * 4 + q];
        a.x = fmaf(v, xv.x, a.x); a.y = fmaf(v, xv.y, a.y);
        a.z = fmaf(v, xv.z, a.z); a.w = fmaf(v, xv.w, a.w);
    }
    return a;
}

// ---------------------------------------------------------------------------
// K2: per-bucket sort (in LDS) + fused gather1: z1 = relu(A @ y1).
// No sorted/meta global round-trip.
// ---------------------------------------------------------------------------
__global__ __launch_bounds__(256) void sort_gather1(const int* __restrict__ BTt,
                                                    const int2* __restrict__ binned,
                                                    const float* __restrict__ Yin,
                                                    float* __restrict__ Z) {
    __shared__ int2 raw[CAP];          // 16 KB
    __shared__ int2 srt[CAP];          // 16 KB
    __shared__ int  cnt[NPB], cur[NPB], aux[4];
    const int tid = threadIdx.x, k = blockIdx.x;

    bucket_sort_lds(BTt, binned, k, tid, raw, srt, cnt, cur, aux);

    const int g = tid >> 2, q = tid & 3;
    const int node = k * NPB + g;
    const int deg = cnt[g];
    const int beg = cur[g] - deg;
    float4 a = gather4(srt, beg, deg, (const float4*)Yin, q);
    if (node < N_NODES) {
        a.x = fmaxf(a.x, 0.f); a.y = fmaxf(a.y, 0.f);
        a.z = fmaxf(a.z, 0.f); a.w = fmaxf(a.w, 0.f);
        ((float4*)Z)[(size_t)node * 4 + q] = a;
    }
}

// ---------------------------------------------------------------------------
// K3: per-bucket sort (in LDS, identical preamble) + gather2 (z2 = A @ z1)
// + [64][17] LDS transpose + out = log_softmax(z2 @ W2).
// 4 lanes/node; lane q owns classes [10q, 10q+10); width-4 shfl reduce.
// ---------------------------------------------------------------------------
__global__ __launch_bounds__(256) void sort_gather_out(const int* __restrict__ BTt,
                                                       const int2* __restrict__ binned,
                                                       const float* __restrict__ Zin,
                                                       const float* __restrict__ W2,
                                                       float* __restrict__ out) {
    __shared__ int2  raw[CAP];                 // 16 KB
    __shared__ int2  srt[CAP];                 // 16 KB
    __shared__ int   cnt[NPB], cur[NPB], aux[4];
    __shared__ float sW2[HIDDEN * N_CLASSES];  // 2.56 KB
    __shared__ float zt[NPB * 17];             // 4.35 KB, +1 pad
    const int tid = threadIdx.x, k = blockIdx.x;

    for (int i = tid; i < HIDDEN * N_CLASSES; i += 256) sW2[i] = W2[i];

    bucket_sort_lds(BTt, binned, k, tid, raw, srt, cnt, cur, aux);

    const int g = tid >> 2, q = tid & 3;
    const int node = k * NPB + g;
    const int deg = cnt[g];
    const int beg = cur[g] - deg;
    const float4 a = gather4(srt, beg, deg, (const float4*)Zin, q);
    zt[g * 17 + q * 4 + 0] = a.x;
    zt[g * 17 + q * 4 + 1] = a.y;
    zt[g * 17 + q * 4 + 2] = a.z;
    zt[g * 17 + q * 4 + 3] = a.w;
    __syncthreads();

    if (node >= N_NODES) return;

    float z[HIDDEN];
#pragma unroll
    for (int kk = 0; kk < HIDDEN; ++kk) z[kk] = zt[g * 17 + kk];

    float oc[10];
#pragma unroll
    for (int c = 0; c < 10; ++c) oc[c] = 0.f;
#pragma unroll
    for (int kk = 0; kk < HIDDEN; ++kk) {
        const float zk = z[kk];
        const float* wr = &sW2[kk * N_CLASSES + q * 10];
#pragma unroll
        for (int c = 0; c < 10; ++c) oc[c] = fmaf(zk, wr[c], oc[c]);
    }
    float m = oc[0];
#pragma unroll
    for (int c = 1; c < 10; ++c) m = fmaxf(m, oc[c]);
#pragma unroll
    for (int d = 1; d < 4; d <<= 1) m = fmaxf(m, __shfl_xor(m, d, 4));
    float se = 0.f;
#pragma unroll
    for (int c = 0; c < 10; ++c) se += __expf(oc[c] - m);
#pragma unroll
    for (int d = 1; d < 4; d <<= 1) se += __shfl_xor(se, d, 4);
    const float lse = m + __logf(se);

    float* orow = out + (size_t)node * N_CLASSES + q * 10;
#pragma unroll
    for (int c = 0; c < 10; ++c) orow[c] = oc[c] - lse;
}

extern "C" void kernel_launch(void* const* d_in, const int* in_sizes, int n_in,
                              void* d_out, int out_size, void* d_ws, size_t ws_size,
                              hipStream_t stream) {
    const float* features = (const float*)d_in[0];  // [50000,100]
    const int*   edge_src = (const int*)d_in[1];    // [800000]
    const int*   edge_dst = (const int*)d_in[2];    // [800000]
    const float* edge_val = (const float*)d_in[3];  // [800000]
    const float* W1       = (const float*)d_in[4];  // [100,16]
    const float* W2       = (const float*)d_in[5];  // [16,40]
    float*       out      = (float*)d_out;          // [50000,40]

    char* base = (char*)d_ws;
    const size_t HNB = (size_t)N_NODES * HIDDEN * sizeof(float);     // 3.2 MB
    float* y1     = (float*)(base);
    float* z1     = (float*)(base + HNB);
    int2*  binned = (int2*) (base + 2 * HNB);                        // 6.4 MB
    int*   BTt    = (int*)  (base + 2 * HNB + (size_t)N_EDGES * 8);  // ~802 KB

    // K1: partition (blocks 0..255) || gemm y1 = X@W1 (blocks 256..1037)
    build_and_gemm<<<PB + GEMMB, 512, 0, stream>>>(edge_src, edge_dst, edge_val,
                                                   features, W1, BTt, binned, y1);
    // K2: in-LDS bucket sort + z1 = relu(A @ y1)
    sort_gather1<<<NBKT, 256, 0, stream>>>(BTt, binned, y1, z1);
    // K3: in-LDS bucket sort + z2 = A @ z1 + log_softmax(z2 @ W2)
    sort_gather_out<<<NBKT, 256, 0, stream>>>(BTt, binned, z1, W2, out);
}